// Round 1
// baseline (51173.215 us; speedup 1.0000x reference)
//
#include <hip/hip_runtime.h>
#include <hip/hip_bf16.h>
#include <cstdint>
#include <cstddef>

#define D    768
#define G3   2304
#define BS   64
#define SEQ  300
#define TDEC 100
#define TCH  25          // encoder gi chunk length (12 chunks of 25)
#define NCH  12
#define NBLK 256         // persistent-kernel grid: 256 blocks x 256 thr, all resident

typedef unsigned int u32;

__device__ __forceinline__ float sigf(float x) { return 1.0f / (1.0f + __expf(-x)); }
__device__ __forceinline__ float tanhfast(float x) {
    float e = __expf(2.0f * x);
    return 1.0f - 2.0f / (e + 1.0f);
}
__device__ __forceinline__ void bf2x(u32 u, float& a, float& b) {
    union { u32 i; float f; } xx, yy;
    xx.i = u << 16; yy.i = u & 0xffff0000u; a = xx.f; b = yy.f;
}
__device__ __forceinline__ float bf1(__hip_bfloat16 h) { return __bfloat162float(h); }

#define DOT4(acc, wv, x0, x1, x2, x3) \
    acc = fmaf((wv).x,(x0), fmaf((wv).y,(x1), fmaf((wv).z,(x2), fmaf((wv).w,(x3),(acc)))))

// ---------------- grid barrier (persistent kernels; NBLK blocks all resident) ----------------
// cnt: monotonic arrival counter (one cacheline). gen: monotonic release flag (separate line).
// Barrier #idx (1-based, uniform across blocks): arrive, last of idx*NBLK releases gen=idx.
struct GBar { u32 cnt; u32 pad0[63]; u32 gen; u32 pad1[63]; };

__device__ __forceinline__ void gridbar(GBar* gb, u32 idx) {
    __syncthreads();
    if (threadIdx.x == 0) {
        __threadfence();                              // release our global writes (agent scope)
        u32 old = atomicAdd(&gb->cnt, 1u);            // device-scope RMW
        if (old == idx * (u32)NBLK - 1u) {
            __hip_atomic_store(&gb->gen, idx, __ATOMIC_RELEASE, __HIP_MEMORY_SCOPE_AGENT);
        } else {
            while (__hip_atomic_load(&gb->gen, __ATOMIC_ACQUIRE, __HIP_MEMORY_SCOPE_AGENT) < idx) {
                __builtin_amdgcn_s_sleep(2);
            }
        }
        __threadfence();                              // acquire for subsequent non-atomic reads
    }
    __syncthreads();
}

// ---------------- kPrep: dec_Wih split, init h/last/out, zero barriers ----------------
__global__ __launch_bounds__(256) void kPrep(
    const float* __restrict__ decWih, const float* __restrict__ tb,
    float* __restrict__ Wc, float* __restrict__ W0,
    float* __restrict__ hE0, float* __restrict__ hD0,
    float* __restrict__ lastP, float* __restrict__ out,
    u32* __restrict__ barz)
{
    if (blockIdx.x == 0 && threadIdx.x < 256) barz[threadIdx.x] = 0;  // 2 GBar structs
    const int NW = G3 * 769;         // 1771776
    const int NH = D * 64;           // 49152
    const int NL = (TDEC + 1) * 64;
    const int NO = 64 * TDEC;
    const int TOT = NW + 2 * NH + NL + NO;
    const float tbv = tb[0];
    const int stride = gridDim.x * blockDim.x;
    for (int u = blockIdx.x * blockDim.x + threadIdx.x; u < TOT; u += stride) {
        if (u < NW) {
            int g = u / 769; int c = u % 769;
            float w = decWih[u];
            if (c == 0) W0[g] = w; else Wc[(size_t)g * D + (c - 1)] = w;
        } else if (u < NW + NH) {
            hE0[u - NW] = 0.0f;
        } else if (u < NW + 2 * NH) {
            hD0[u - NW - NH] = 0.0f;
        } else if (u < NW + 2 * NH + NL) {
            int i = u - NW - 2 * NH;
            lastP[i] = (i < 64) ? 0.0f : tbv;   // lastP[t][b]: pred sums seeded with tb
        } else {
            out[u - NW - 2 * NH - NL] = tbv;    // out seeded with tb; cell phase atomicAdds
        }
    }
}

// ---------------- gi tile: gi[t][gj][b] = (x[b,t,:]+pe[t,:]) . Wih[gj,:]  (bf16 out) ----------------
// 64x64 tile at (m0, tc), K-chunk 16, 256 threads. As/Bs: 1024 floats each.
__device__ __forceinline__ void gi_tile(
    const float* __restrict__ x, const float* __restrict__ Wih,
    __hip_bfloat16* __restrict__ giB, float* __restrict__ As, float* __restrict__ Bs,
    int m0, int tc, int t)
{
    const int tid = threadIdx.x;
    const int lr = tid >> 2;
    const int lk = (tid & 3) * 4;
    const int tm = (tid >> 4) * 4;
    const int tn = (tid & 15) * 4;
    const float tf = (float)t;

    float acc[4][4];
    #pragma unroll
    for (int i = 0; i < 4; ++i)
        #pragma unroll
        for (int j = 0; j < 4; ++j) acc[i][j] = 0.f;

    for (int kc = 0; kc < D; kc += 16) {
        const float4 a4 = *(const float4*)(Wih + (size_t)(m0 + lr) * D + kc + lk);
        float4 b4 = *(const float4*)(x + ((size_t)lr * SEQ + t) * D + kc + lk);
        // PE inline: pe[even]=sin(t*dv), pe[odd]=cos(t*dv), dv=exp(-0.02398526*i)
        const int i0 = (kc + lk) >> 1;
        const float dv0 = __expf(-0.0239852614f * (float)i0);
        const float dv1 = __expf(-0.0239852614f * (float)(i0 + 1));
        float s0, c0, s1, c1;
        __sincosf(tf * dv0, &s0, &c0);
        __sincosf(tf * dv1, &s1, &c1);
        b4.x += s0; b4.y += c0; b4.z += s1; b4.w += c1;
        As[(lk + 0) * 64 + lr] = a4.x; As[(lk + 1) * 64 + lr] = a4.y;
        As[(lk + 2) * 64 + lr] = a4.z; As[(lk + 3) * 64 + lr] = a4.w;
        Bs[(lk + 0) * 64 + lr] = b4.x; Bs[(lk + 1) * 64 + lr] = b4.y;
        Bs[(lk + 2) * 64 + lr] = b4.z; Bs[(lk + 3) * 64 + lr] = b4.w;
        __syncthreads();
        #pragma unroll
        for (int k = 0; k < 16; ++k) {
            const float4 av = *(const float4*)(As + k * 64 + tm);
            const float4 bv = *(const float4*)(Bs + k * 64 + tn);
            acc[0][0] = fmaf(av.x, bv.x, acc[0][0]); acc[0][1] = fmaf(av.x, bv.y, acc[0][1]);
            acc[0][2] = fmaf(av.x, bv.z, acc[0][2]); acc[0][3] = fmaf(av.x, bv.w, acc[0][3]);
            acc[1][0] = fmaf(av.y, bv.x, acc[1][0]); acc[1][1] = fmaf(av.y, bv.y, acc[1][1]);
            acc[1][2] = fmaf(av.y, bv.z, acc[1][2]); acc[1][3] = fmaf(av.y, bv.w, acc[1][3]);
            acc[2][0] = fmaf(av.z, bv.x, acc[2][0]); acc[2][1] = fmaf(av.z, bv.y, acc[2][1]);
            acc[2][2] = fmaf(av.z, bv.z, acc[2][2]); acc[2][3] = fmaf(av.z, bv.w, acc[2][3]);
            acc[3][0] = fmaf(av.w, bv.x, acc[3][0]); acc[3][1] = fmaf(av.w, bv.y, acc[3][1]);
            acc[3][2] = fmaf(av.w, bv.z, acc[3][2]); acc[3][3] = fmaf(av.w, bv.w, acc[3][3]);
        }
        __syncthreads();
    }
    #pragma unroll
    for (int i = 0; i < 4; ++i) {
        __hip_bfloat16* row = giB + ((size_t)tc * G3 + m0 + tm + i) * 64 + tn;
        row[0] = __float2bfloat16(acc[i][0]);
        row[1] = __float2bfloat16(acc[i][1]);
        row[2] = __float2bfloat16(acc[i][2]);
        row[3] = __float2bfloat16(acc[i][3]);
    }
}

// ---------------- encoder recurrence step (blocks 0..191, 4 waves = 4 j-rows) ----------------
__device__ __forceinline__ void enc_step(
    const __hip_bfloat16* __restrict__ giT, const float* __restrict__ Whh,
    const float* __restrict__ bih, const float* __restrict__ bhh,
    const float* __restrict__ hrd, float* __restrict__ hwr,
    __hip_bfloat16* __restrict__ encB, int t, float* __restrict__ lds_h)
{
    const int tid = threadIdx.x;
    const int b   = tid & 63;
    const int jw  = __builtin_amdgcn_readfirstlane((int)(blockIdx.x * 4 + (tid >> 6)));

    const float* whr = Whh + (size_t)jw * D;
    const float* whz = Whh + (size_t)(768 + jw) * D;
    const float* whn = Whh + (size_t)(1536 + jw) * D;

    float ahr = 0.f, ahz = 0.f, ahn = 0.f;
    for (int kc = 0; kc < D; kc += 64) {
        const float4* gh = (const float4*)(hrd + kc * 64);
        float4* lh = (float4*)lds_h;
        #pragma unroll
        for (int it = 0; it < 4; ++it) lh[tid + 256 * it] = gh[tid + 256 * it];
        __syncthreads();
        #pragma unroll
        for (int kk = 0; kk < 64; kk += 4) {
            const float4 v3 = *(const float4*)(whr + kc + kk);
            const float4 v4 = *(const float4*)(whz + kc + kk);
            const float4 v5 = *(const float4*)(whn + kc + kk);
            const float h0 = lds_h[(kk + 0) * 64 + b];
            const float h1 = lds_h[(kk + 1) * 64 + b];
            const float h2 = lds_h[(kk + 2) * 64 + b];
            const float h3 = lds_h[(kk + 3) * 64 + b];
            DOT4(ahr, v3, h0, h1, h2, h3);
            DOT4(ahz, v4, h0, h1, h2, h3);
            DOT4(ahn, v5, h0, h1, h2, h3);
        }
        __syncthreads();
    }
    const float gir = bf1(giT[(size_t)jw * 64 + b]);
    const float giz = bf1(giT[(size_t)(768 + jw) * 64 + b]);
    const float gin = bf1(giT[(size_t)(1536 + jw) * 64 + b]);
    const float r = sigf(gir + bih[jw] + ahr + bhh[jw]);
    const float z = sigf(giz + bih[768 + jw] + ahz + bhh[768 + jw]);
    const float n = tanhfast(gin + bih[1536 + jw] + r * (ahn + bhh[1536 + jw]));
    const float ho = hrd[jw * 64 + b];
    const float hn = (1.f - z) * n + z * ho;
    hwr[jw * 64 + b] = hn;
    encB[((size_t)b * SEQ + t) * D + jw] = __float2bfloat16(hn);
}

// ---------------- kEncPersist: whole encoder in ONE launch ----------------
__global__ __launch_bounds__(256) void kEncPersist(
    const float* __restrict__ x, const float* __restrict__ eWih,
    const float* __restrict__ eWhh, const float* __restrict__ ebih,
    const float* __restrict__ ebhh, __hip_bfloat16* __restrict__ giB,
    float* __restrict__ hE0, float* __restrict__ hE1,
    __hip_bfloat16* __restrict__ encB, GBar* gb)
{
    __shared__ float smem[4096];   // GI: As=smem[0:1024), Bs=smem[1024:2048); step: lds_h all 4096
    u32 bars = 0;
    for (int c = 0; c < NCH; ++c) {
        // GI phase: 900 tile jobs strided over NBLK blocks
        for (int job = blockIdx.x; job < 36 * TCH; job += NBLK) {
            gi_tile(x, eWih, giB, smem, smem + 1024,
                    (job % 36) * 64, job / 36, c * TCH + job / 36);
        }
        gridbar(gb, ++bars);
        // 25 recurrence steps
        for (int tc = 0; tc < TCH; ++tc) {
            const int t = c * TCH + tc;
            if (blockIdx.x < 192) {
                const float* hr = (t & 1) ? hE1 : hE0;
                float*       hw = (t & 1) ? hE0 : hE1;
                enc_step(giB + (size_t)tc * G3 * 64, eWhh, ebih, ebhh, hr, hw, encB, t, smem);
            }
            gridbar(gb, ++bars);
        }
    }
}

// ---------------- kGemmMem: mem = enc @ mW^T + mb  (bf16 A, fp32 B, bf16 out) ----------------
__global__ __launch_bounds__(256) void kGemmMem(
    const __hip_bfloat16* __restrict__ encB, const float* __restrict__ mW,
    const float* __restrict__ mb, __hip_bfloat16* __restrict__ memB)
{
    __shared__ float As[16 * 64];
    __shared__ float Bs[16 * 64];
    const int tid = threadIdx.x;
    const int m0 = blockIdx.y * 64, n0 = blockIdx.x * 64;
    const int lr = tid >> 2;
    const int lk = (tid & 3) * 4;
    const int tm = (tid >> 4) * 4;
    const int tn = (tid & 15) * 4;

    float acc[4][4];
    #pragma unroll
    for (int i = 0; i < 4; ++i)
        #pragma unroll
        for (int j = 0; j < 4; ++j) acc[i][j] = 0.f;

    for (int kc = 0; kc < D; kc += 16) {
        const uint2 ua = *(const uint2*)(encB + (size_t)(m0 + lr) * D + kc + lk);
        float a0, a1, a2, a3;
        bf2x(ua.x, a0, a1); bf2x(ua.y, a2, a3);
        const float4 b4 = *(const float4*)(mW + (size_t)(n0 + lr) * D + kc + lk);
        As[(lk + 0) * 64 + lr] = a0; As[(lk + 1) * 64 + lr] = a1;
        As[(lk + 2) * 64 + lr] = a2; As[(lk + 3) * 64 + lr] = a3;
        Bs[(lk + 0) * 64 + lr] = b4.x; Bs[(lk + 1) * 64 + lr] = b4.y;
        Bs[(lk + 2) * 64 + lr] = b4.z; Bs[(lk + 3) * 64 + lr] = b4.w;
        __syncthreads();
        #pragma unroll
        for (int k = 0; k < 16; ++k) {
            const float4 av = *(const float4*)(As + k * 64 + tm);
            const float4 bv = *(const float4*)(Bs + k * 64 + tn);
            acc[0][0] = fmaf(av.x, bv.x, acc[0][0]); acc[0][1] = fmaf(av.x, bv.y, acc[0][1]);
            acc[0][2] = fmaf(av.x, bv.z, acc[0][2]); acc[0][3] = fmaf(av.x, bv.w, acc[0][3]);
            acc[1][0] = fmaf(av.y, bv.x, acc[1][0]); acc[1][1] = fmaf(av.y, bv.y, acc[1][1]);
            acc[1][2] = fmaf(av.y, bv.z, acc[1][2]); acc[1][3] = fmaf(av.y, bv.w, acc[1][3]);
            acc[2][0] = fmaf(av.z, bv.x, acc[2][0]); acc[2][1] = fmaf(av.z, bv.y, acc[2][1]);
            acc[2][2] = fmaf(av.z, bv.z, acc[2][2]); acc[2][3] = fmaf(av.z, bv.w, acc[2][3]);
            acc[3][0] = fmaf(av.w, bv.x, acc[3][0]); acc[3][1] = fmaf(av.w, bv.y, acc[3][1]);
            acc[3][2] = fmaf(av.w, bv.z, acc[3][2]); acc[3][3] = fmaf(av.w, bv.w, acc[3][3]);
        }
        __syncthreads();
    }
    const float bb0 = mb[n0 + tn + 0], bb1 = mb[n0 + tn + 1];
    const float bb2 = mb[n0 + tn + 2], bb3 = mb[n0 + tn + 3];
    #pragma unroll
    for (int i = 0; i < 4; ++i) {
        __hip_bfloat16* row = memB + (size_t)(m0 + tm + i) * D + n0 + tn;
        row[0] = __float2bfloat16(acc[i][0] + bb0);
        row[1] = __float2bfloat16(acc[i][1] + bb1);
        row[2] = __float2bfloat16(acc[i][2] + bb2);
        row[3] = __float2bfloat16(acc[i][3] + bb3);
    }
}

// ---------------- decoder phase: q (blocks 0..191) ----------------
__device__ __forceinline__ void dec_q(
    const float* __restrict__ qW, const float* __restrict__ qb,
    const float* __restrict__ hrd, float* __restrict__ qT, float* __restrict__ lds_h)
{
    const int tid = threadIdx.x;
    const int b   = tid & 63;
    const int jw  = __builtin_amdgcn_readfirstlane((int)(blockIdx.x * 4 + (tid >> 6)));
    const float* w = qW + (size_t)jw * D;
    float acc = 0.f;
    for (int kc = 0; kc < D; kc += 64) {
        const float4* gh = (const float4*)(hrd + kc * 64);
        float4* lh = (float4*)lds_h;
        #pragma unroll
        for (int it = 0; it < 4; ++it) lh[tid + 256 * it] = gh[tid + 256 * it];
        __syncthreads();
        #pragma unroll
        for (int kk = 0; kk < 64; kk += 4) {
            const float4 w4 = *(const float4*)(w + kc + kk);
            acc = fmaf(w4.x, lds_h[(kk + 0) * 64 + b], acc);
            acc = fmaf(w4.y, lds_h[(kk + 1) * 64 + b], acc);
            acc = fmaf(w4.z, lds_h[(kk + 2) * 64 + b], acc);
            acc = fmaf(w4.w, lds_h[(kk + 3) * 64 + b], acc);
        }
        __syncthreads();
    }
    qT[(size_t)b * D + jw] = acc + qb[jw];
}

// ---------------- decoder phase: tanh-attention, 4 ctx partials (all 256 blocks) ----------------
// block = (b = blk&63, ch = blk>>6 in 0..3), 75 rows/block, 4 waves
__device__ __forceinline__ void dec_attn(
    const float* __restrict__ qT, const __hip_bfloat16* __restrict__ memB,
    const __hip_bfloat16* __restrict__ encB, const float* __restrict__ pW,
    const float* __restrict__ pb, float* __restrict__ ctxP, float* __restrict__ seP,
    float* __restrict__ sm)
{
    const int tid = threadIdx.x;
    const int b  = blockIdx.x & 63;
    const int ch = blockIdx.x >> 6;
    float* s_q  = sm;
    float* s_pw = sm + 768;
    float* s_cx = sm + 1536;
    float* s_se = sm + 2304;
    for (int i = tid; i < 768; i += 256) {
        s_q[i]  = qT[(size_t)b * D + i];
        s_pw[i] = pW[i];
        s_cx[i] = 0.f;
    }
    if (tid == 0) s_se[0] = 0.f;
    __syncthreads();
    const int lane = tid & 63;
    const int wv   = tid >> 6;
    float cacc[12];
    #pragma unroll
    for (int i = 0; i < 12; ++i) cacc[i] = 0.f;
    float seacc = 0.f;
    const float pbv = pb[0];
    const int s0 = ch * 75;
    for (int s = s0 + wv; s < s0 + 75; s += 4) {
        const __hip_bfloat16* mrow = memB + ((size_t)b * SEQ + s) * D;
        const __hip_bfloat16* erow = encB + ((size_t)b * SEQ + s) * D;
        float lp = 0.f;
        #pragma unroll
        for (int g = 0; g < 3; ++g) {
            const int d0 = g * 256 + lane * 4;
            const uint2 mu = *(const uint2*)(mrow + d0);
            float m0, m1, m2, m3;
            bf2x(mu.x, m0, m1); bf2x(mu.y, m2, m3);
            const float4 qv = *(const float4*)(s_q + d0);
            const float4 pv = *(const float4*)(s_pw + d0);
            lp = fmaf(pv.x, tanhfast(m0 + qv.x), lp);
            lp = fmaf(pv.y, tanhfast(m1 + qv.y), lp);
            lp = fmaf(pv.z, tanhfast(m2 + qv.z), lp);
            lp = fmaf(pv.w, tanhfast(m3 + qv.w), lp);
        }
        #pragma unroll
        for (int o = 32; o > 0; o >>= 1) lp += __shfl_xor(lp, o, 64);
        const float e = __expf(lp + pbv);    // identical on all 64 lanes
        seacc += e;
        #pragma unroll
        for (int g = 0; g < 3; ++g) {
            const int d0 = g * 256 + lane * 4;
            const uint2 eu = *(const uint2*)(erow + d0);
            float e0, e1, e2, e3;
            bf2x(eu.x, e0, e1); bf2x(eu.y, e2, e3);
            cacc[g * 4 + 0] = fmaf(e, e0, cacc[g * 4 + 0]);
            cacc[g * 4 + 1] = fmaf(e, e1, cacc[g * 4 + 1]);
            cacc[g * 4 + 2] = fmaf(e, e2, cacc[g * 4 + 2]);
            cacc[g * 4 + 3] = fmaf(e, e3, cacc[g * 4 + 3]);
        }
    }
    #pragma unroll
    for (int g = 0; g < 3; ++g) {
        const int d0 = g * 256 + lane * 4;
        atomicAdd(&s_cx[d0 + 0], cacc[g * 4 + 0]);
        atomicAdd(&s_cx[d0 + 1], cacc[g * 4 + 1]);
        atomicAdd(&s_cx[d0 + 2], cacc[g * 4 + 2]);
        atomicAdd(&s_cx[d0 + 3], cacc[g * 4 + 3]);
    }
    if (lane == 0) atomicAdd(&s_se[0], seacc);
    __syncthreads();
    for (int i = tid; i < 768; i += 256) ctxP[((size_t)ch * 768 + i) * 64 + b] = s_cx[i];
    if (tid == 0) seP[ch * 64 + b] = s_se[0];
}

// ---------------- decoder phase: GRU cell + pred (blocks 0..191) ----------------
__device__ __forceinline__ void dec_cell(
    const float* __restrict__ Wc, const float* __restrict__ W0,
    const float* __restrict__ dWhh, const float* __restrict__ dbih,
    const float* __restrict__ dbhh, const float* __restrict__ tW,
    const float* __restrict__ ctxP, const float* __restrict__ seP,
    const float* __restrict__ lastT, float* __restrict__ lastN,
    const float* __restrict__ hrd, float* __restrict__ hwr,
    float* __restrict__ out, int t,
    float* __restrict__ lds_h, float* __restrict__ lds_c)
{
    const int tid = threadIdx.x;
    const int b   = tid & 63;
    const int jw  = __builtin_amdgcn_readfirstlane((int)(blockIdx.x * 4 + (tid >> 6)));
    const float* whr = dWhh + (size_t)jw * D;
    const float* whz = dWhh + (size_t)(768 + jw) * D;
    const float* whn = dWhh + (size_t)(1536 + jw) * D;
    const float* wcr = Wc + (size_t)jw * D;
    const float* wcz = Wc + (size_t)(768 + jw) * D;
    const float* wcn = Wc + (size_t)(1536 + jw) * D;
    float cir = 0.f, ciz = 0.f, cin_ = 0.f, ahr = 0.f, ahz = 0.f, ahn = 0.f;
    for (int kc = 0; kc < D; kc += 64) {
        const float4* gh = (const float4*)(hrd + kc * 64);
        const float4* g0 = (const float4*)(ctxP + (size_t)kc * 64);
        const float4* g1 = (const float4*)(ctxP + (size_t)(768 + kc) * 64);
        const float4* g2 = (const float4*)(ctxP + (size_t)(1536 + kc) * 64);
        const float4* g3 = (const float4*)(ctxP + (size_t)(2304 + kc) * 64);
        float4* lh = (float4*)lds_h;
        float4* lc = (float4*)lds_c;
        #pragma unroll
        for (int it = 0; it < 4; ++it) {
            lh[tid + 256 * it] = gh[tid + 256 * it];
            const float4 u0 = g0[tid + 256 * it];
            const float4 u1 = g1[tid + 256 * it];
            const float4 u2 = g2[tid + 256 * it];
            const float4 u3 = g3[tid + 256 * it];
            float4 s;
            s.x = u0.x + u1.x + u2.x + u3.x;
            s.y = u0.y + u1.y + u2.y + u3.y;
            s.z = u0.z + u1.z + u2.z + u3.z;
            s.w = u0.w + u1.w + u2.w + u3.w;
            lc[tid + 256 * it] = s;
        }
        __syncthreads();
        #pragma unroll
        for (int kk = 0; kk < 64; kk += 4) {
            const float4 v0 = *(const float4*)(wcr + kc + kk);
            const float4 v1 = *(const float4*)(wcz + kc + kk);
            const float4 v2 = *(const float4*)(wcn + kc + kk);
            const float4 v3 = *(const float4*)(whr + kc + kk);
            const float4 v4 = *(const float4*)(whz + kc + kk);
            const float4 v5 = *(const float4*)(whn + kc + kk);
            const float c0 = lds_c[(kk + 0) * 64 + b];
            const float c1 = lds_c[(kk + 1) * 64 + b];
            const float c2 = lds_c[(kk + 2) * 64 + b];
            const float c3 = lds_c[(kk + 3) * 64 + b];
            const float h0 = lds_h[(kk + 0) * 64 + b];
            const float h1 = lds_h[(kk + 1) * 64 + b];
            const float h2 = lds_h[(kk + 2) * 64 + b];
            const float h3 = lds_h[(kk + 3) * 64 + b];
            DOT4(cir, v0, c0, c1, c2, c3);
            DOT4(ciz, v1, c0, c1, c2, c3);
            DOT4(cin_, v2, c0, c1, c2, c3);
            DOT4(ahr, v3, h0, h1, h2, h3);
            DOT4(ahz, v4, h0, h1, h2, h3);
            DOT4(ahn, v5, h0, h1, h2, h3);
        }
        __syncthreads();
    }
    const float se = seP[b] + seP[64 + b] + seP[128 + b] + seP[192 + b];
    const float inv = 1.f / se;
    const float lst = lastT[b];
    const float gir = cir * inv + W0[jw] * lst + dbih[jw];
    const float giz = ciz * inv + W0[768 + jw] * lst + dbih[768 + jw];
    const float gin = cin_ * inv + W0[1536 + jw] * lst + dbih[1536 + jw];
    const float r = sigf(gir + ahr + dbhh[jw]);
    const float z = sigf(giz + ahz + dbhh[768 + jw]);
    const float n = tanhfast(gin + r * (ahn + dbhh[1536 + jw]));
    const float ho = hrd[jw * 64 + b];
    const float hn = (1.f - z) * n + z * ho;
    hwr[jw * 64 + b] = hn;

    // pred partial: out[b][t] += sum_j tW[j] * hn[j][b]  (out pre-seeded with tb)
    __syncthreads();
    lds_h[(tid >> 6) * 64 + b] = tW[jw] * hn;
    __syncthreads();
    if (tid < 64) {
        const float p = lds_h[tid] + lds_h[64 + tid] + lds_h[128 + tid] + lds_h[192 + tid];
        atomicAdd(&out[(size_t)tid * TDEC + t], p);
        atomicAdd(&lastN[tid], p);
    }
}

// ---------------- kDecPersist: whole decoder in ONE launch ----------------
__global__ __launch_bounds__(256) void kDecPersist(
    const float* __restrict__ Wc, const float* __restrict__ W0,
    const float* __restrict__ dWhh, const float* __restrict__ dbih,
    const float* __restrict__ dbhh, const float* __restrict__ tW,
    const float* __restrict__ qW, const float* __restrict__ qb,
    const __hip_bfloat16* __restrict__ memB, const __hip_bfloat16* __restrict__ encB,
    const float* __restrict__ pW, const float* __restrict__ pb,
    float* __restrict__ ctxP, float* __restrict__ seP, float* __restrict__ lastP,
    float* __restrict__ hD0, float* __restrict__ hD1,
    float* __restrict__ qT, float* __restrict__ out, GBar* gb)
{
    __shared__ float smem[8192];   // q: 4096; attn: 2305; cell: lds_h=smem[0:4096), lds_c=smem[4096:8192)
    u32 bars = 0;
    for (int t = 0; t < TDEC; ++t) {
        const float* hr = (t & 1) ? hD1 : hD0;
        float*       hw = (t & 1) ? hD0 : hD1;
        if (blockIdx.x < 192) dec_q(qW, qb, hr, qT, smem);
        gridbar(gb, ++bars);
        dec_attn(qT, memB, encB, pW, pb, ctxP, seP, smem);
        gridbar(gb, ++bars);
        if (blockIdx.x < 192) dec_cell(Wc, W0, dWhh, dbih, dbhh, tW, ctxP, seP,
                                       lastP + t * 64, lastP + (t + 1) * 64,
                                       hr, hw, out, t, smem, smem + 4096);
        gridbar(gb, ++bars);
    }
}

// ---------------- launch ----------------
extern "C" void kernel_launch(void* const* d_in, const int* in_sizes, int n_in,
                              void* d_out, int out_size, void* d_ws, size_t ws_size,
                              hipStream_t stream) {
    const float* x    = (const float*)d_in[0];
    const float* eWih = (const float*)d_in[1];
    const float* eWhh = (const float*)d_in[2];
    const float* ebih = (const float*)d_in[3];
    const float* ebhh = (const float*)d_in[4];
    const float* dWih = (const float*)d_in[5];
    const float* dWhh = (const float*)d_in[6];
    const float* dbih = (const float*)d_in[7];
    const float* dbhh = (const float*)d_in[8];
    const float* qW   = (const float*)d_in[9];
    const float* qb   = (const float*)d_in[10];
    const float* mW   = (const float*)d_in[11];
    const float* mb   = (const float*)d_in[12];
    const float* pW   = (const float*)d_in[13];
    const float* pb   = (const float*)d_in[14];
    const float* tW   = (const float*)d_in[15];
    const float* tb   = (const float*)d_in[16];
    float* out = (float*)d_out;

    char* w = (char*)d_ws;
    auto alloc = [&](size_t bytes) -> char* {
        char* p = w; w += (bytes + 255) & ~(size_t)255; return p;
    };
    // total ~76 MB
    float* Wc    = (float*)alloc((size_t)G3 * D * 4);
    float* W0    = (float*)alloc((size_t)G3 * 4);
    __hip_bfloat16* encB = (__hip_bfloat16*)alloc((size_t)BS * SEQ * D * 2);
    __hip_bfloat16* memB = (__hip_bfloat16*)alloc((size_t)BS * SEQ * D * 2);
    __hip_bfloat16* giB  = (__hip_bfloat16*)alloc((size_t)TCH * G3 * 64 * 2);
    float* hE0   = (float*)alloc((size_t)D * 64 * 4);
    float* hE1   = (float*)alloc((size_t)D * 64 * 4);
    float* hD0   = (float*)alloc((size_t)D * 64 * 4);
    float* hD1   = (float*)alloc((size_t)D * 64 * 4);
    float* qT    = (float*)alloc((size_t)BS * D * 4);
    float* ctxP  = (float*)alloc((size_t)4 * D * 64 * 4);
    float* seP   = (float*)alloc(4 * 64 * 4);
    float* lastP = (float*)alloc((TDEC + 1) * 64 * 4);
    GBar*  bars  = (GBar*)alloc(2 * sizeof(GBar));   // [0]=enc, [1]=dec

    kPrep<<<512, 256, 0, stream>>>(dWih, tb, Wc, W0, hE0, hD0, lastP, out, (u32*)bars);
    kEncPersist<<<NBLK, 256, 0, stream>>>(x, eWih, eWhh, ebih, ebhh, giB, hE0, hE1, encB, bars + 0);
    kGemmMem<<<dim3(12, 300), 256, 0, stream>>>(encB, mW, mb, memB);
    kDecPersist<<<NBLK, 256, 0, stream>>>(Wc, W0, dWhh, dbih, dbhh, tW, qW, qb,
                                          memB, encB, pW, pb, ctxP, seP, lastP,
                                          hD0, hD1, qT, out, bars + 1);
}

// Round 2
// 29647.632 us; speedup vs baseline: 1.7260x; 1.7260x over previous
//
#include <hip/hip_runtime.h>
#include <hip/hip_bf16.h>
#include <cstdint>
#include <cstddef>

#define D    768
#define G3   2304
#define BS   64
#define SEQ  300
#define TDEC 100
#define TCH  25          // encoder gi chunk length (12 chunks of 25)
#define NCH  12
#define NBLK 256         // persistent-kernel grid: 256 blocks x 256 thr, all resident

typedef unsigned int u32;

__device__ __forceinline__ float sigf(float x) { return 1.0f / (1.0f + __expf(-x)); }
__device__ __forceinline__ float tanhfast(float x) {
    float e = __expf(2.0f * x);
    return 1.0f - 2.0f / (e + 1.0f);
}
__device__ __forceinline__ void bf2x(u32 u, float& a, float& b) {
    union { u32 i; float f; } xx, yy;
    xx.i = u << 16; yy.i = u & 0xffff0000u; a = xx.f; b = yy.f;
}
__device__ __forceinline__ float bf1(__hip_bfloat16 h) { return __bfloat162float(h); }

#define DOT4(acc, wv, x0, x1, x2, x3) \
    acc = fmaf((wv).x,(x0), fmaf((wv).y,(x1), fmaf((wv).z,(x2), fmaf((wv).w,(x3),(acc)))))

// ---------------- grid barrier (persistent kernels; NBLK blocks all resident) ----------------
// cnt: monotonic arrival counter (one cacheline). gen: monotonic release flag (separate line).
// Barrier #idx (1-based, uniform across blocks).
// KEY: poll with RELAXED atomic loads (plain sc1 load, no L2 invalidate); exactly ONE
// release fence (buffer_wbl2) before arrival and ONE acquire fence (buffer_inv) at exit.
// Round-1 version polled with ACQUIRE -> buffer_inv per iteration -> continuous whole-L2
// invalidation on every XCD -> 89 us/barrier. This version: O(us) per barrier.
struct GBar { u32 cnt; u32 pad0[63]; u32 gen; u32 pad1[63]; };

__device__ __forceinline__ void gridbar(GBar* gb, u32 idx) {
    __syncthreads();
    if (threadIdx.x == 0) {
        __builtin_amdgcn_fence(__ATOMIC_RELEASE, "agent");   // wbl2: drain our writes to coherence point
        u32 old = __hip_atomic_fetch_add(&gb->cnt, 1u, __ATOMIC_RELAXED, __HIP_MEMORY_SCOPE_AGENT);
        if (old == idx * (u32)NBLK - 1u) {
            __hip_atomic_store(&gb->gen, idx, __ATOMIC_RELAXED, __HIP_MEMORY_SCOPE_AGENT);
        } else {
            while (__hip_atomic_load(&gb->gen, __ATOMIC_RELAXED, __HIP_MEMORY_SCOPE_AGENT) < idx) {
                __builtin_amdgcn_s_sleep(8);
            }
        }
        __builtin_amdgcn_fence(__ATOMIC_ACQUIRE, "agent");   // inv: L1+L2 invalidate, once
    }
    __syncthreads();
}

// ---------------- kPrep: dec_Wih split, init h/last/out, zero barriers ----------------
__global__ __launch_bounds__(256) void kPrep(
    const float* __restrict__ decWih, const float* __restrict__ tb,
    float* __restrict__ Wc, float* __restrict__ W0,
    float* __restrict__ hE0, float* __restrict__ hD0,
    float* __restrict__ lastP, float* __restrict__ out,
    u32* __restrict__ barz)
{
    if (blockIdx.x == 0 && threadIdx.x < 256) barz[threadIdx.x] = 0;  // 2 GBar structs
    const int NW = G3 * 769;         // 1771776
    const int NH = D * 64;           // 49152
    const int NL = (TDEC + 1) * 64;
    const int NO = 64 * TDEC;
    const int TOT = NW + 2 * NH + NL + NO;
    const float tbv = tb[0];
    const int stride = gridDim.x * blockDim.x;
    for (int u = blockIdx.x * blockDim.x + threadIdx.x; u < TOT; u += stride) {
        if (u < NW) {
            int g = u / 769; int c = u % 769;
            float w = decWih[u];
            if (c == 0) W0[g] = w; else Wc[(size_t)g * D + (c - 1)] = w;
        } else if (u < NW + NH) {
            hE0[u - NW] = 0.0f;
        } else if (u < NW + 2 * NH) {
            hD0[u - NW - NH] = 0.0f;
        } else if (u < NW + 2 * NH + NL) {
            int i = u - NW - 2 * NH;
            lastP[i] = (i < 64) ? 0.0f : tbv;   // lastP[t][b]: pred sums seeded with tb
        } else {
            out[u - NW - 2 * NH - NL] = tbv;    // out seeded with tb; cell phase atomicAdds
        }
    }
}

// ---------------- gi tile: gi[t][gj][b] = (x[b,t,:]+pe[t,:]) . Wih[gj,:]  (bf16 out) ----------------
// 64x64 tile at (m0, tc), K-chunk 16, 256 threads. As/Bs: 1024 floats each.
__device__ __forceinline__ void gi_tile(
    const float* __restrict__ x, const float* __restrict__ Wih,
    __hip_bfloat16* __restrict__ giB, float* __restrict__ As, float* __restrict__ Bs,
    int m0, int tc, int t)
{
    const int tid = threadIdx.x;
    const int lr = tid >> 2;
    const int lk = (tid & 3) * 4;
    const int tm = (tid >> 4) * 4;
    const int tn = (tid & 15) * 4;
    const float tf = (float)t;

    float acc[4][4];
    #pragma unroll
    for (int i = 0; i < 4; ++i)
        #pragma unroll
        for (int j = 0; j < 4; ++j) acc[i][j] = 0.f;

    for (int kc = 0; kc < D; kc += 16) {
        const float4 a4 = *(const float4*)(Wih + (size_t)(m0 + lr) * D + kc + lk);
        float4 b4 = *(const float4*)(x + ((size_t)lr * SEQ + t) * D + kc + lk);
        // PE inline: pe[even]=sin(t*dv), pe[odd]=cos(t*dv), dv=exp(-0.02398526*i)
        const int i0 = (kc + lk) >> 1;
        const float dv0 = __expf(-0.0239852614f * (float)i0);
        const float dv1 = __expf(-0.0239852614f * (float)(i0 + 1));
        float s0, c0, s1, c1;
        __sincosf(tf * dv0, &s0, &c0);
        __sincosf(tf * dv1, &s1, &c1);
        b4.x += s0; b4.y += c0; b4.z += s1; b4.w += c1;
        As[(lk + 0) * 64 + lr] = a4.x; As[(lk + 1) * 64 + lr] = a4.y;
        As[(lk + 2) * 64 + lr] = a4.z; As[(lk + 3) * 64 + lr] = a4.w;
        Bs[(lk + 0) * 64 + lr] = b4.x; Bs[(lk + 1) * 64 + lr] = b4.y;
        Bs[(lk + 2) * 64 + lr] = b4.z; Bs[(lk + 3) * 64 + lr] = b4.w;
        __syncthreads();
        #pragma unroll
        for (int k = 0; k < 16; ++k) {
            const float4 av = *(const float4*)(As + k * 64 + tm);
            const float4 bv = *(const float4*)(Bs + k * 64 + tn);
            acc[0][0] = fmaf(av.x, bv.x, acc[0][0]); acc[0][1] = fmaf(av.x, bv.y, acc[0][1]);
            acc[0][2] = fmaf(av.x, bv.z, acc[0][2]); acc[0][3] = fmaf(av.x, bv.w, acc[0][3]);
            acc[1][0] = fmaf(av.y, bv.x, acc[1][0]); acc[1][1] = fmaf(av.y, bv.y, acc[1][1]);
            acc[1][2] = fmaf(av.y, bv.z, acc[1][2]); acc[1][3] = fmaf(av.y, bv.w, acc[1][3]);
            acc[2][0] = fmaf(av.z, bv.x, acc[2][0]); acc[2][1] = fmaf(av.z, bv.y, acc[2][1]);
            acc[2][2] = fmaf(av.z, bv.z, acc[2][2]); acc[2][3] = fmaf(av.z, bv.w, acc[2][3]);
            acc[3][0] = fmaf(av.w, bv.x, acc[3][0]); acc[3][1] = fmaf(av.w, bv.y, acc[3][1]);
            acc[3][2] = fmaf(av.w, bv.z, acc[3][2]); acc[3][3] = fmaf(av.w, bv.w, acc[3][3]);
        }
        __syncthreads();
    }
    #pragma unroll
    for (int i = 0; i < 4; ++i) {
        __hip_bfloat16* row = giB + ((size_t)tc * G3 + m0 + tm + i) * 64 + tn;
        row[0] = __float2bfloat16(acc[i][0]);
        row[1] = __float2bfloat16(acc[i][1]);
        row[2] = __float2bfloat16(acc[i][2]);
        row[3] = __float2bfloat16(acc[i][3]);
    }
}

// ---------------- encoder recurrence step (blocks 0..191, 4 waves = 4 j-rows) ----------------
__device__ __forceinline__ void enc_step(
    const __hip_bfloat16* __restrict__ giT, const float* __restrict__ Whh,
    const float* __restrict__ bih, const float* __restrict__ bhh,
    const float* __restrict__ hrd, float* __restrict__ hwr,
    __hip_bfloat16* __restrict__ encB, int t, float* __restrict__ lds_h)
{
    const int tid = threadIdx.x;
    const int b   = tid & 63;
    const int jw  = __builtin_amdgcn_readfirstlane((int)(blockIdx.x * 4 + (tid >> 6)));

    const float* whr = Whh + (size_t)jw * D;
    const float* whz = Whh + (size_t)(768 + jw) * D;
    const float* whn = Whh + (size_t)(1536 + jw) * D;

    float ahr = 0.f, ahz = 0.f, ahn = 0.f;
    for (int kc = 0; kc < D; kc += 64) {
        const float4* gh = (const float4*)(hrd + kc * 64);
        float4* lh = (float4*)lds_h;
        #pragma unroll
        for (int it = 0; it < 4; ++it) lh[tid + 256 * it] = gh[tid + 256 * it];
        __syncthreads();
        #pragma unroll
        for (int kk = 0; kk < 64; kk += 4) {
            const float4 v3 = *(const float4*)(whr + kc + kk);
            const float4 v4 = *(const float4*)(whz + kc + kk);
            const float4 v5 = *(const float4*)(whn + kc + kk);
            const float h0 = lds_h[(kk + 0) * 64 + b];
            const float h1 = lds_h[(kk + 1) * 64 + b];
            const float h2 = lds_h[(kk + 2) * 64 + b];
            const float h3 = lds_h[(kk + 3) * 64 + b];
            DOT4(ahr, v3, h0, h1, h2, h3);
            DOT4(ahz, v4, h0, h1, h2, h3);
            DOT4(ahn, v5, h0, h1, h2, h3);
        }
        __syncthreads();
    }
    const float gir = bf1(giT[(size_t)jw * 64 + b]);
    const float giz = bf1(giT[(size_t)(768 + jw) * 64 + b]);
    const float gin = bf1(giT[(size_t)(1536 + jw) * 64 + b]);
    const float r = sigf(gir + bih[jw] + ahr + bhh[jw]);
    const float z = sigf(giz + bih[768 + jw] + ahz + bhh[768 + jw]);
    const float n = tanhfast(gin + bih[1536 + jw] + r * (ahn + bhh[1536 + jw]));
    const float ho = hrd[jw * 64 + b];
    const float hn = (1.f - z) * n + z * ho;
    hwr[jw * 64 + b] = hn;
    encB[((size_t)b * SEQ + t) * D + jw] = __float2bfloat16(hn);
}

// ---------------- kEncPersist: whole encoder in ONE launch ----------------
__global__ __launch_bounds__(256) void kEncPersist(
    const float* __restrict__ x, const float* __restrict__ eWih,
    const float* __restrict__ eWhh, const float* __restrict__ ebih,
    const float* __restrict__ ebhh, __hip_bfloat16* __restrict__ giB,
    float* __restrict__ hE0, float* __restrict__ hE1,
    __hip_bfloat16* __restrict__ encB, GBar* gb)
{
    __shared__ float smem[4096];   // GI: As=smem[0:1024), Bs=smem[1024:2048); step: lds_h all 4096
    u32 bars = 0;
    for (int c = 0; c < NCH; ++c) {
        // GI phase: 900 tile jobs strided over NBLK blocks
        for (int job = blockIdx.x; job < 36 * TCH; job += NBLK) {
            gi_tile(x, eWih, giB, smem, smem + 1024,
                    (job % 36) * 64, job / 36, c * TCH + job / 36);
        }
        gridbar(gb, ++bars);
        // 25 recurrence steps
        for (int tc = 0; tc < TCH; ++tc) {
            const int t = c * TCH + tc;
            if (blockIdx.x < 192) {
                const float* hr = (t & 1) ? hE1 : hE0;
                float*       hw = (t & 1) ? hE0 : hE1;
                enc_step(giB + (size_t)tc * G3 * 64, eWhh, ebih, ebhh, hr, hw, encB, t, smem);
            }
            gridbar(gb, ++bars);
        }
    }
}

// ---------------- kGemmMem: mem = enc @ mW^T + mb  (bf16 A, fp32 B, bf16 out) ----------------
__global__ __launch_bounds__(256) void kGemmMem(
    const __hip_bfloat16* __restrict__ encB, const float* __restrict__ mW,
    const float* __restrict__ mb, __hip_bfloat16* __restrict__ memB)
{
    __shared__ float As[16 * 64];
    __shared__ float Bs[16 * 64];
    const int tid = threadIdx.x;
    const int m0 = blockIdx.y * 64, n0 = blockIdx.x * 64;
    const int lr = tid >> 2;
    const int lk = (tid & 3) * 4;
    const int tm = (tid >> 4) * 4;
    const int tn = (tid & 15) * 4;

    float acc[4][4];
    #pragma unroll
    for (int i = 0; i < 4; ++i)
        #pragma unroll
        for (int j = 0; j < 4; ++j) acc[i][j] = 0.f;

    for (int kc = 0; kc < D; kc += 16) {
        const uint2 ua = *(const uint2*)(encB + (size_t)(m0 + lr) * D + kc + lk);
        float a0, a1, a2, a3;
        bf2x(ua.x, a0, a1); bf2x(ua.y, a2, a3);
        const float4 b4 = *(const float4*)(mW + (size_t)(n0 + lr) * D + kc + lk);
        As[(lk + 0) * 64 + lr] = a0; As[(lk + 1) * 64 + lr] = a1;
        As[(lk + 2) * 64 + lr] = a2; As[(lk + 3) * 64 + lr] = a3;
        Bs[(lk + 0) * 64 + lr] = b4.x; Bs[(lk + 1) * 64 + lr] = b4.y;
        Bs[(lk + 2) * 64 + lr] = b4.z; Bs[(lk + 3) * 64 + lr] = b4.w;
        __syncthreads();
        #pragma unroll
        for (int k = 0; k < 16; ++k) {
            const float4 av = *(const float4*)(As + k * 64 + tm);
            const float4 bv = *(const float4*)(Bs + k * 64 + tn);
            acc[0][0] = fmaf(av.x, bv.x, acc[0][0]); acc[0][1] = fmaf(av.x, bv.y, acc[0][1]);
            acc[0][2] = fmaf(av.x, bv.z, acc[0][2]); acc[0][3] = fmaf(av.x, bv.w, acc[0][3]);
            acc[1][0] = fmaf(av.y, bv.x, acc[1][0]); acc[1][1] = fmaf(av.y, bv.y, acc[1][1]);
            acc[1][2] = fmaf(av.y, bv.z, acc[1][2]); acc[1][3] = fmaf(av.y, bv.w, acc[1][3]);
            acc[2][0] = fmaf(av.z, bv.x, acc[2][0]); acc[2][1] = fmaf(av.z, bv.y, acc[2][1]);
            acc[2][2] = fmaf(av.z, bv.z, acc[2][2]); acc[2][3] = fmaf(av.z, bv.w, acc[2][3]);
            acc[3][0] = fmaf(av.w, bv.x, acc[3][0]); acc[3][1] = fmaf(av.w, bv.y, acc[3][1]);
            acc[3][2] = fmaf(av.w, bv.z, acc[3][2]); acc[3][3] = fmaf(av.w, bv.w, acc[3][3]);
        }
        __syncthreads();
    }
    const float bb0 = mb[n0 + tn + 0], bb1 = mb[n0 + tn + 1];
    const float bb2 = mb[n0 + tn + 2], bb3 = mb[n0 + tn + 3];
    #pragma unroll
    for (int i = 0; i < 4; ++i) {
        __hip_bfloat16* row = memB + (size_t)(m0 + tm + i) * D + n0 + tn;
        row[0] = __float2bfloat16(acc[i][0] + bb0);
        row[1] = __float2bfloat16(acc[i][1] + bb1);
        row[2] = __float2bfloat16(acc[i][2] + bb2);
        row[3] = __float2bfloat16(acc[i][3] + bb3);
    }
}

// ---------------- decoder phase: q (blocks 0..191) ----------------
__device__ __forceinline__ void dec_q(
    const float* __restrict__ qW, const float* __restrict__ qb,
    const float* __restrict__ hrd, float* __restrict__ qT, float* __restrict__ lds_h)
{
    const int tid = threadIdx.x;
    const int b   = tid & 63;
    const int jw  = __builtin_amdgcn_readfirstlane((int)(blockIdx.x * 4 + (tid >> 6)));
    const float* w = qW + (size_t)jw * D;
    float acc = 0.f;
    for (int kc = 0; kc < D; kc += 64) {
        const float4* gh = (const float4*)(hrd + kc * 64);
        float4* lh = (float4*)lds_h;
        #pragma unroll
        for (int it = 0; it < 4; ++it) lh[tid + 256 * it] = gh[tid + 256 * it];
        __syncthreads();
        #pragma unroll
        for (int kk = 0; kk < 64; kk += 4) {
            const float4 w4 = *(const float4*)(w + kc + kk);
            acc = fmaf(w4.x, lds_h[(kk + 0) * 64 + b], acc);
            acc = fmaf(w4.y, lds_h[(kk + 1) * 64 + b], acc);
            acc = fmaf(w4.z, lds_h[(kk + 2) * 64 + b], acc);
            acc = fmaf(w4.w, lds_h[(kk + 3) * 64 + b], acc);
        }
        __syncthreads();
    }
    qT[(size_t)b * D + jw] = acc + qb[jw];
}

// ---------------- decoder phase: tanh-attention, 4 ctx partials (all 256 blocks) ----------------
// block = (b = blk&63, ch = blk>>6 in 0..3), 75 rows/block, 4 waves
__device__ __forceinline__ void dec_attn(
    const float* __restrict__ qT, const __hip_bfloat16* __restrict__ memB,
    const __hip_bfloat16* __restrict__ encB, const float* __restrict__ pW,
    const float* __restrict__ pb, float* __restrict__ ctxP, float* __restrict__ seP,
    float* __restrict__ sm)
{
    const int tid = threadIdx.x;
    const int b  = blockIdx.x & 63;
    const int ch = blockIdx.x >> 6;
    float* s_q  = sm;
    float* s_pw = sm + 768;
    float* s_cx = sm + 1536;
    float* s_se = sm + 2304;
    for (int i = tid; i < 768; i += 256) {
        s_q[i]  = qT[(size_t)b * D + i];
        s_pw[i] = pW[i];
        s_cx[i] = 0.f;
    }
    if (tid == 0) s_se[0] = 0.f;
    __syncthreads();
    const int lane = tid & 63;
    const int wv   = tid >> 6;
    float cacc[12];
    #pragma unroll
    for (int i = 0; i < 12; ++i) cacc[i] = 0.f;
    float seacc = 0.f;
    const float pbv = pb[0];
    const int s0 = ch * 75;
    for (int s = s0 + wv; s < s0 + 75; s += 4) {
        const __hip_bfloat16* mrow = memB + ((size_t)b * SEQ + s) * D;
        const __hip_bfloat16* erow = encB + ((size_t)b * SEQ + s) * D;
        float lp = 0.f;
        #pragma unroll
        for (int g = 0; g < 3; ++g) {
            const int d0 = g * 256 + lane * 4;
            const uint2 mu = *(const uint2*)(mrow + d0);
            float m0, m1, m2, m3;
            bf2x(mu.x, m0, m1); bf2x(mu.y, m2, m3);
            const float4 qv = *(const float4*)(s_q + d0);
            const float4 pv = *(const float4*)(s_pw + d0);
            lp = fmaf(pv.x, tanhfast(m0 + qv.x), lp);
            lp = fmaf(pv.y, tanhfast(m1 + qv.y), lp);
            lp = fmaf(pv.z, tanhfast(m2 + qv.z), lp);
            lp = fmaf(pv.w, tanhfast(m3 + qv.w), lp);
        }
        #pragma unroll
        for (int o = 32; o > 0; o >>= 1) lp += __shfl_xor(lp, o, 64);
        const float e = __expf(lp + pbv);    // identical on all 64 lanes
        seacc += e;
        #pragma unroll
        for (int g = 0; g < 3; ++g) {
            const int d0 = g * 256 + lane * 4;
            const uint2 eu = *(const uint2*)(erow + d0);
            float e0, e1, e2, e3;
            bf2x(eu.x, e0, e1); bf2x(eu.y, e2, e3);
            cacc[g * 4 + 0] = fmaf(e, e0, cacc[g * 4 + 0]);
            cacc[g * 4 + 1] = fmaf(e, e1, cacc[g * 4 + 1]);
            cacc[g * 4 + 2] = fmaf(e, e2, cacc[g * 4 + 2]);
            cacc[g * 4 + 3] = fmaf(e, e3, cacc[g * 4 + 3]);
        }
    }
    #pragma unroll
    for (int g = 0; g < 3; ++g) {
        const int d0 = g * 256 + lane * 4;
        atomicAdd(&s_cx[d0 + 0], cacc[g * 4 + 0]);
        atomicAdd(&s_cx[d0 + 1], cacc[g * 4 + 1]);
        atomicAdd(&s_cx[d0 + 2], cacc[g * 4 + 2]);
        atomicAdd(&s_cx[d0 + 3], cacc[g * 4 + 3]);
    }
    if (lane == 0) atomicAdd(&s_se[0], seacc);
    __syncthreads();
    for (int i = tid; i < 768; i += 256) ctxP[((size_t)ch * 768 + i) * 64 + b] = s_cx[i];
    if (tid == 0) seP[ch * 64 + b] = s_se[0];
}

// ---------------- decoder phase: GRU cell + pred (blocks 0..191) ----------------
__device__ __forceinline__ void dec_cell(
    const float* __restrict__ Wc, const float* __restrict__ W0,
    const float* __restrict__ dWhh, const float* __restrict__ dbih,
    const float* __restrict__ dbhh, const float* __restrict__ tW,
    const float* __restrict__ ctxP, const float* __restrict__ seP,
    const float* __restrict__ lastT, float* __restrict__ lastN,
    const float* __restrict__ hrd, float* __restrict__ hwr,
    float* __restrict__ out, int t,
    float* __restrict__ lds_h, float* __restrict__ lds_c)
{
    const int tid = threadIdx.x;
    const int b   = tid & 63;
    const int jw  = __builtin_amdgcn_readfirstlane((int)(blockIdx.x * 4 + (tid >> 6)));
    const float* whr = dWhh + (size_t)jw * D;
    const float* whz = dWhh + (size_t)(768 + jw) * D;
    const float* whn = dWhh + (size_t)(1536 + jw) * D;
    const float* wcr = Wc + (size_t)jw * D;
    const float* wcz = Wc + (size_t)(768 + jw) * D;
    const float* wcn = Wc + (size_t)(1536 + jw) * D;
    float cir = 0.f, ciz = 0.f, cin_ = 0.f, ahr = 0.f, ahz = 0.f, ahn = 0.f;
    for (int kc = 0; kc < D; kc += 64) {
        const float4* gh = (const float4*)(hrd + kc * 64);
        const float4* g0 = (const float4*)(ctxP + (size_t)kc * 64);
        const float4* g1 = (const float4*)(ctxP + (size_t)(768 + kc) * 64);
        const float4* g2 = (const float4*)(ctxP + (size_t)(1536 + kc) * 64);
        const float4* g3 = (const float4*)(ctxP + (size_t)(2304 + kc) * 64);
        float4* lh = (float4*)lds_h;
        float4* lc = (float4*)lds_c;
        #pragma unroll
        for (int it = 0; it < 4; ++it) {
            lh[tid + 256 * it] = gh[tid + 256 * it];
            const float4 u0 = g0[tid + 256 * it];
            const float4 u1 = g1[tid + 256 * it];
            const float4 u2 = g2[tid + 256 * it];
            const float4 u3 = g3[tid + 256 * it];
            float4 s;
            s.x = u0.x + u1.x + u2.x + u3.x;
            s.y = u0.y + u1.y + u2.y + u3.y;
            s.z = u0.z + u1.z + u2.z + u3.z;
            s.w = u0.w + u1.w + u2.w + u3.w;
            lc[tid + 256 * it] = s;
        }
        __syncthreads();
        #pragma unroll
        for (int kk = 0; kk < 64; kk += 4) {
            const float4 v0 = *(const float4*)(wcr + kc + kk);
            const float4 v1 = *(const float4*)(wcz + kc + kk);
            const float4 v2 = *(const float4*)(wcn + kc + kk);
            const float4 v3 = *(const float4*)(whr + kc + kk);
            const float4 v4 = *(const float4*)(whz + kc + kk);
            const float4 v5 = *(const float4*)(whn + kc + kk);
            const float c0 = lds_c[(kk + 0) * 64 + b];
            const float c1 = lds_c[(kk + 1) * 64 + b];
            const float c2 = lds_c[(kk + 2) * 64 + b];
            const float c3 = lds_c[(kk + 3) * 64 + b];
            const float h0 = lds_h[(kk + 0) * 64 + b];
            const float h1 = lds_h[(kk + 1) * 64 + b];
            const float h2 = lds_h[(kk + 2) * 64 + b];
            const float h3 = lds_h[(kk + 3) * 64 + b];
            DOT4(cir, v0, c0, c1, c2, c3);
            DOT4(ciz, v1, c0, c1, c2, c3);
            DOT4(cin_, v2, c0, c1, c2, c3);
            DOT4(ahr, v3, h0, h1, h2, h3);
            DOT4(ahz, v4, h0, h1, h2, h3);
            DOT4(ahn, v5, h0, h1, h2, h3);
        }
        __syncthreads();
    }
    const float se = seP[b] + seP[64 + b] + seP[128 + b] + seP[192 + b];
    const float inv = 1.f / se;
    const float lst = lastT[b];
    const float gir = cir * inv + W0[jw] * lst + dbih[jw];
    const float giz = ciz * inv + W0[768 + jw] * lst + dbih[768 + jw];
    const float gin = cin_ * inv + W0[1536 + jw] * lst + dbih[1536 + jw];
    const float r = sigf(gir + ahr + dbhh[jw]);
    const float z = sigf(giz + ahz + dbhh[768 + jw]);
    const float n = tanhfast(gin + r * (ahn + dbhh[1536 + jw]));
    const float ho = hrd[jw * 64 + b];
    const float hn = (1.f - z) * n + z * ho;
    hwr[jw * 64 + b] = hn;

    // pred partial: out[b][t] += sum_j tW[j] * hn[j][b]  (out pre-seeded with tb)
    __syncthreads();
    lds_h[(tid >> 6) * 64 + b] = tW[jw] * hn;
    __syncthreads();
    if (tid < 64) {
        const float p = lds_h[tid] + lds_h[64 + tid] + lds_h[128 + tid] + lds_h[192 + tid];
        atomicAdd(&out[(size_t)tid * TDEC + t], p);
        atomicAdd(&lastN[tid], p);
    }
}

// ---------------- kDecPersist: whole decoder in ONE launch ----------------
__global__ __launch_bounds__(256) void kDecPersist(
    const float* __restrict__ Wc, const float* __restrict__ W0,
    const float* __restrict__ dWhh, const float* __restrict__ dbih,
    const float* __restrict__ dbhh, const float* __restrict__ tW,
    const float* __restrict__ qW, const float* __restrict__ qb,
    const __hip_bfloat16* __restrict__ memB, const __hip_bfloat16* __restrict__ encB,
    const float* __restrict__ pW, const float* __restrict__ pb,
    float* __restrict__ ctxP, float* __restrict__ seP, float* __restrict__ lastP,
    float* __restrict__ hD0, float* __restrict__ hD1,
    float* __restrict__ qT, float* __restrict__ out, GBar* gb)
{
    __shared__ float smem[8192];   // q: 4096; attn: 2305; cell: lds_h=smem[0:4096), lds_c=smem[4096:8192)
    u32 bars = 0;
    for (int t = 0; t < TDEC; ++t) {
        const float* hr = (t & 1) ? hD1 : hD0;
        float*       hw = (t & 1) ? hD0 : hD1;
        if (blockIdx.x < 192) dec_q(qW, qb, hr, qT, smem);
        gridbar(gb, ++bars);
        dec_attn(qT, memB, encB, pW, pb, ctxP, seP, smem);
        gridbar(gb, ++bars);
        if (blockIdx.x < 192) dec_cell(Wc, W0, dWhh, dbih, dbhh, tW, ctxP, seP,
                                       lastP + t * 64, lastP + (t + 1) * 64,
                                       hr, hw, out, t, smem, smem + 4096);
        gridbar(gb, ++bars);
    }
}

// ---------------- launch ----------------
extern "C" void kernel_launch(void* const* d_in, const int* in_sizes, int n_in,
                              void* d_out, int out_size, void* d_ws, size_t ws_size,
                              hipStream_t stream) {
    const float* x    = (const float*)d_in[0];
    const float* eWih = (const float*)d_in[1];
    const float* eWhh = (const float*)d_in[2];
    const float* ebih = (const float*)d_in[3];
    const float* ebhh = (const float*)d_in[4];
    const float* dWih = (const float*)d_in[5];
    const float* dWhh = (const float*)d_in[6];
    const float* dbih = (const float*)d_in[7];
    const float* dbhh = (const float*)d_in[8];
    const float* qW   = (const float*)d_in[9];
    const float* qb   = (const float*)d_in[10];
    const float* mW   = (const float*)d_in[11];
    const float* mb   = (const float*)d_in[12];
    const float* pW   = (const float*)d_in[13];
    const float* pb   = (const float*)d_in[14];
    const float* tW   = (const float*)d_in[15];
    const float* tb   = (const float*)d_in[16];
    float* out = (float*)d_out;

    char* w = (char*)d_ws;
    auto alloc = [&](size_t bytes) -> char* {
        char* p = w; w += (bytes + 255) & ~(size_t)255; return p;
    };
    // total ~76 MB
    float* Wc    = (float*)alloc((size_t)G3 * D * 4);
    float* W0    = (float*)alloc((size_t)G3 * 4);
    __hip_bfloat16* encB = (__hip_bfloat16*)alloc((size_t)BS * SEQ * D * 2);
    __hip_bfloat16* memB = (__hip_bfloat16*)alloc((size_t)BS * SEQ * D * 2);
    __hip_bfloat16* giB  = (__hip_bfloat16*)alloc((size_t)TCH * G3 * 64 * 2);
    float* hE0   = (float*)alloc((size_t)D * 64 * 4);
    float* hE1   = (float*)alloc((size_t)D * 64 * 4);
    float* hD0   = (float*)alloc((size_t)D * 64 * 4);
    float* hD1   = (float*)alloc((size_t)D * 64 * 4);
    float* qT    = (float*)alloc((size_t)BS * D * 4);
    float* ctxP  = (float*)alloc((size_t)4 * D * 64 * 4);
    float* seP   = (float*)alloc(4 * 64 * 4);
    float* lastP = (float*)alloc((TDEC + 1) * 64 * 4);
    GBar*  bars  = (GBar*)alloc(2 * sizeof(GBar));   // [0]=enc, [1]=dec

    kPrep<<<512, 256, 0, stream>>>(dWih, tb, Wc, W0, hE0, hD0, lastP, out, (u32*)bars);
    kEncPersist<<<NBLK, 256, 0, stream>>>(x, eWih, eWhh, ebih, ebhh, giB, hE0, hE1, encB, bars + 0);
    kGemmMem<<<dim3(12, 300), 256, 0, stream>>>(encB, mW, mb, memB);
    kDecPersist<<<NBLK, 256, 0, stream>>>(Wc, W0, dWhh, dbih, dbhh, tW, qW, qb,
                                          memB, encB, pW, pb, ctxP, seP, lastP,
                                          hD0, hD1, qT, out, bars + 1);
}

// Round 3
// 28018.634 us; speedup vs baseline: 1.8264x; 1.0581x over previous
//
#include <hip/hip_runtime.h>
#include <hip/hip_bf16.h>
#include <cstdint>
#include <cstddef>

#define D    768
#define G3   2304
#define BS   64
#define SEQ  300
#define TDEC 100
#define TCH  25          // encoder gi chunk length (12 chunks of 25)
#define NCH  12
#define NBLK 256         // persistent-kernel grid: 256 blocks x 256 thr, all resident
#define NH   (D * 64)    // one h-state buffer (fp32 elems)
#define GENIDX 288       // gen word index inside a barrier struct (u32 units)
#define BARWORDS 320     // per-barrier struct size in u32 (flags[256] + pad + gen + pad)

typedef unsigned int u32;
typedef unsigned long long u64;

__device__ __forceinline__ float sigf(float x) { return 1.0f / (1.0f + __expf(-x)); }
__device__ __forceinline__ float tanhfast(float x) {
    float e = __expf(2.0f * x);
    return 1.0f - 2.0f / (e + 1.0f);
}
__device__ __forceinline__ void bf2x(u32 u, float& a, float& b) {
    union { u32 i; float f; } xx, yy;
    xx.i = u << 16; yy.i = u & 0xffff0000u; a = xx.f; b = yy.f;
}

#define DOT4(acc, wv, x0, x1, x2, x3) \
    acc = fmaf((wv).x,(x0), fmaf((wv).y,(x1), fmaf((wv).z,(x2), fmaf((wv).w,(x3),(acc)))))

// ---------- coherent (IF-level) access helpers: sc0 sc1 write-through / bypass ----------
__device__ __forceinline__ void stG(float* p, float v) {
    __hip_atomic_store(p, v, __ATOMIC_RELAXED, __HIP_MEMORY_SCOPE_AGENT);
}
__device__ __forceinline__ void stG64(u64* p, u64 v) {
    __hip_atomic_store(p, v, __ATOMIC_RELAXED, __HIP_MEMORY_SCOPE_AGENT);
}
__device__ __forceinline__ float ldGf(const float* p) {
    return __hip_atomic_load(p, __ATOMIC_RELAXED, __HIP_MEMORY_SCOPE_AGENT);
}
__device__ __forceinline__ u32 ldGu(const u32* p) {
    return __hip_atomic_load(p, __ATOMIC_RELAXED, __HIP_MEMORY_SCOPE_AGENT);
}
__device__ __forceinline__ u32 f2bfu(float f) {
    __hip_bfloat16 h = __float2bfloat16(f);
    unsigned short s; __builtin_memcpy(&s, &h, 2); return (u32)s;
}
__device__ __forceinline__ float bfsel(u32 w, int sh) {
    union { u32 i; float f; } u; u.i = ((w >> sh) & 0xffffu) << 16; return u.f;
}

// ---------------- grid barrier: flag array + monitor block, NO cache maintenance ----------------
// Arrival: workgroup release fence (s_waitcnt only; all cross-block data is sc0sc1
// write-through, so vmcnt-drain == device-visible) -> block writes its own flag (no RMW).
// Block 0 = monitor: thread tid polls flags[tid]; then tid0 publishes gen. Waiters poll gen.
// All values monotonic generations -> no reset, overwrite-safe.
__device__ __forceinline__ void gridbar(u32* bar, u32 idx) {
    __builtin_amdgcn_fence(__ATOMIC_RELEASE, "workgroup");   // drains vmcnt; no wbl2/inv
    __syncthreads();
    const int tid = threadIdx.x;
    if (blockIdx.x == 0) {
        if (tid > 0) {
            while (__hip_atomic_load(&bar[tid], __ATOMIC_RELAXED, __HIP_MEMORY_SCOPE_AGENT) < idx)
                __builtin_amdgcn_s_sleep(2);
        }
        __syncthreads();
        if (tid == 0)
            __hip_atomic_store(&bar[GENIDX], idx, __ATOMIC_RELAXED, __HIP_MEMORY_SCOPE_AGENT);
    } else {
        if (tid == 0) {
            __hip_atomic_store(&bar[blockIdx.x], idx, __ATOMIC_RELAXED, __HIP_MEMORY_SCOPE_AGENT);
            while (__hip_atomic_load(&bar[GENIDX], __ATOMIC_RELAXED, __HIP_MEMORY_SCOPE_AGENT) < idx)
                __builtin_amdgcn_s_sleep(2);
        }
        __syncthreads();
    }
}

// ---------------- kPrep: dec_Wih split, init h/last/out, zero barrier words ----------------
__global__ __launch_bounds__(256) void kPrep(
    const float* __restrict__ decWih, const float* __restrict__ tb,
    float* __restrict__ Wc, float* __restrict__ W0,
    float* __restrict__ hE0, float* __restrict__ hD0,
    float* __restrict__ lastP, float* __restrict__ out,
    u32* __restrict__ barW)
{
    const int NW = G3 * 769;         // 1771776
    const int NL = (TDEC + 1) * 64;
    const int NO = 64 * TDEC;
    const int NB = 2 * BARWORDS;
    const int TOT = NW + 2 * NH + NL + NO + NB;
    const float tbv = tb[0];
    const int stride = gridDim.x * blockDim.x;
    for (int u = blockIdx.x * blockDim.x + threadIdx.x; u < TOT; u += stride) {
        if (u < NW) {
            int g = u / 769; int c = u % 769;
            float w = decWih[u];
            if (c == 0) W0[g] = w; else Wc[(size_t)g * D + (c - 1)] = w;
        } else if (u < NW + NH) {
            hE0[u - NW] = 0.0f;                 // hSeq[0]
        } else if (u < NW + 2 * NH) {
            hD0[u - NW - NH] = 0.0f;            // hDseq[0]
        } else if (u < NW + 2 * NH + NL) {
            int i = u - NW - 2 * NH;
            lastP[i] = (i < 64) ? 0.0f : tbv;   // lastP[t][b]: pred sums seeded with tb
        } else if (u < NW + 2 * NH + NL + NO) {
            out[u - NW - 2 * NH - NL] = tbv;    // out seeded with tb; cell phase atomicAdds
        } else {
            barW[u - NW - 2 * NH - NL - NO] = 0;
        }
    }
}

// ---------------- gi tile: gi[t][gj][b] = (x[b,t,:]+pe[t,:]) . Wih[gj,:]  (bf16 out, IF-write) ----------------
__device__ __forceinline__ void gi_tile(
    const float* __restrict__ x, const float* __restrict__ Wih,
    __hip_bfloat16* __restrict__ giB, float* __restrict__ As, float* __restrict__ Bs,
    int m0, int tc, int t)
{
    const int tid = threadIdx.x;
    const int lr = tid >> 2;
    const int lk = (tid & 3) * 4;
    const int tm = (tid >> 4) * 4;
    const int tn = (tid & 15) * 4;
    const float tf = (float)t;

    float acc[4][4];
    #pragma unroll
    for (int i = 0; i < 4; ++i)
        #pragma unroll
        for (int j = 0; j < 4; ++j) acc[i][j] = 0.f;

    for (int kc = 0; kc < D; kc += 16) {
        const float4 a4 = *(const float4*)(Wih + (size_t)(m0 + lr) * D + kc + lk);
        float4 b4 = *(const float4*)(x + ((size_t)lr * SEQ + t) * D + kc + lk);
        const int i0 = (kc + lk) >> 1;
        const float dv0 = __expf(-0.0239852614f * (float)i0);
        const float dv1 = __expf(-0.0239852614f * (float)(i0 + 1));
        float s0, c0, s1, c1;
        __sincosf(tf * dv0, &s0, &c0);
        __sincosf(tf * dv1, &s1, &c1);
        b4.x += s0; b4.y += c0; b4.z += s1; b4.w += c1;
        As[(lk + 0) * 64 + lr] = a4.x; As[(lk + 1) * 64 + lr] = a4.y;
        As[(lk + 2) * 64 + lr] = a4.z; As[(lk + 3) * 64 + lr] = a4.w;
        Bs[(lk + 0) * 64 + lr] = b4.x; Bs[(lk + 1) * 64 + lr] = b4.y;
        Bs[(lk + 2) * 64 + lr] = b4.z; Bs[(lk + 3) * 64 + lr] = b4.w;
        __syncthreads();
        #pragma unroll
        for (int k = 0; k < 16; ++k) {
            const float4 av = *(const float4*)(As + k * 64 + tm);
            const float4 bv = *(const float4*)(Bs + k * 64 + tn);
            acc[0][0] = fmaf(av.x, bv.x, acc[0][0]); acc[0][1] = fmaf(av.x, bv.y, acc[0][1]);
            acc[0][2] = fmaf(av.x, bv.z, acc[0][2]); acc[0][3] = fmaf(av.x, bv.w, acc[0][3]);
            acc[1][0] = fmaf(av.y, bv.x, acc[1][0]); acc[1][1] = fmaf(av.y, bv.y, acc[1][1]);
            acc[1][2] = fmaf(av.y, bv.z, acc[1][2]); acc[1][3] = fmaf(av.y, bv.w, acc[1][3]);
            acc[2][0] = fmaf(av.z, bv.x, acc[2][0]); acc[2][1] = fmaf(av.z, bv.y, acc[2][1]);
            acc[2][2] = fmaf(av.z, bv.z, acc[2][2]); acc[2][3] = fmaf(av.z, bv.w, acc[2][3]);
            acc[3][0] = fmaf(av.w, bv.x, acc[3][0]); acc[3][1] = fmaf(av.w, bv.y, acc[3][1]);
            acc[3][2] = fmaf(av.w, bv.z, acc[3][2]); acc[3][3] = fmaf(av.w, bv.w, acc[3][3]);
        }
        __syncthreads();
    }
    // pack 4 bf16 -> one 8B write-through store per output row
    #pragma unroll
    for (int i = 0; i < 4; ++i) {
        u32 lo = f2bfu(acc[i][0]) | (f2bfu(acc[i][1]) << 16);
        u32 hi = f2bfu(acc[i][2]) | (f2bfu(acc[i][3]) << 16);
        u64 v = ((u64)hi << 32) | (u64)lo;
        stG64((u64*)(giB + ((size_t)tc * G3 + m0 + tm + i) * 64 + tn), v);
    }
}

// ---------------- encoder recurrence step (blocks 0..191, 4 waves = 4 j-rows) ----------------
// hrd: unique-per-step buffer (cached reads on fresh lines); hwr: write-through.
__device__ __forceinline__ void enc_step(
    const __hip_bfloat16* __restrict__ giT, const float* __restrict__ Whh,
    const float* __restrict__ bih, const float* __restrict__ bhh,
    const float* __restrict__ hrd, float* __restrict__ hwr,
    __hip_bfloat16* __restrict__ encB, int t, float* __restrict__ lds_h)
{
    const int tid = threadIdx.x;
    const int b   = tid & 63;
    const int jw  = __builtin_amdgcn_readfirstlane((int)(blockIdx.x * 4 + (tid >> 6)));

    const float* whr = Whh + (size_t)jw * D;
    const float* whz = Whh + (size_t)(768 + jw) * D;
    const float* whn = Whh + (size_t)(1536 + jw) * D;

    float ahr = 0.f, ahz = 0.f, ahn = 0.f;
    for (int kc = 0; kc < D; kc += 64) {
        const float4* gh = (const float4*)(hrd + kc * 64);
        float4* lh = (float4*)lds_h;
        #pragma unroll
        for (int it = 0; it < 4; ++it) lh[tid + 256 * it] = gh[tid + 256 * it];
        __syncthreads();
        #pragma unroll
        for (int kk = 0; kk < 64; kk += 4) {
            const float4 v3 = *(const float4*)(whr + kc + kk);
            const float4 v4 = *(const float4*)(whz + kc + kk);
            const float4 v5 = *(const float4*)(whn + kc + kk);
            const float h0 = lds_h[(kk + 0) * 64 + b];
            const float h1 = lds_h[(kk + 1) * 64 + b];
            const float h2 = lds_h[(kk + 2) * 64 + b];
            const float h3 = lds_h[(kk + 3) * 64 + b];
            DOT4(ahr, v3, h0, h1, h2, h3);
            DOT4(ahz, v4, h0, h1, h2, h3);
            DOT4(ahn, v5, h0, h1, h2, h3);
        }
        __syncthreads();
    }
    // gi: 3 coherent u32 loads (pairs of bf16; pick half by b&1) — giB ring is IF-only
    const u32* gp = (const u32*)giT;
    const int bo = b >> 1, sh = (b & 1) << 4;
    const u32 w0 = ldGu(gp + (size_t)jw * 32 + bo);
    const u32 w1 = ldGu(gp + (size_t)(768 + jw) * 32 + bo);
    const u32 w2 = ldGu(gp + (size_t)(1536 + jw) * 32 + bo);
    const float gir = bfsel(w0, sh);
    const float giz = bfsel(w1, sh);
    const float gin = bfsel(w2, sh);
    const float r = sigf(gir + bih[jw] + ahr + bhh[jw]);
    const float z = sigf(giz + bih[768 + jw] + ahz + bhh[768 + jw]);
    const float n = tanhfast(gin + bih[1536 + jw] + r * (ahn + bhh[1536 + jw]));
    const float ho = hrd[jw * 64 + b];
    const float hn = (1.f - z) * n + z * ho;
    stG(hwr + jw * 64 + b, hn);                         // write-through for next step
    encB[((size_t)b * SEQ + t) * D + jw] = __float2bfloat16(hn);  // write-only: dispatch flush
}

// ---------------- kEncPersist: whole encoder in ONE launch ----------------
__global__ __launch_bounds__(256) void kEncPersist(
    const float* __restrict__ x, const float* __restrict__ eWih,
    const float* __restrict__ eWhh, const float* __restrict__ ebih,
    const float* __restrict__ ebhh, __hip_bfloat16* __restrict__ giB,
    float* __restrict__ hSeq, __hip_bfloat16* __restrict__ encB, u32* bar)
{
    __shared__ float smem[4096];
    u32 bars = 0;
    for (int c = 0; c < NCH; ++c) {
        for (int job = blockIdx.x; job < 36 * TCH; job += NBLK) {
            gi_tile(x, eWih, giB, smem, smem + 1024,
                    (job % 36) * 64, job / 36, c * TCH + job / 36);
        }
        gridbar(bar, ++bars);
        for (int tc = 0; tc < TCH; ++tc) {
            const int t = c * TCH + tc;
            if (blockIdx.x < 192) {
                enc_step(giB + (size_t)tc * G3 * 64, eWhh, ebih, ebhh,
                         hSeq + (size_t)t * NH, hSeq + (size_t)(t + 1) * NH, encB, t, smem);
            }
            gridbar(bar, ++bars);
        }
    }
}

// ---------------- kGemmMem: mem = enc @ mW^T + mb  (bf16 A, fp32 B, bf16 out) ----------------
__global__ __launch_bounds__(256) void kGemmMem(
    const __hip_bfloat16* __restrict__ encB, const float* __restrict__ mW,
    const float* __restrict__ mb, __hip_bfloat16* __restrict__ memB)
{
    __shared__ float As[16 * 64];
    __shared__ float Bs[16 * 64];
    const int tid = threadIdx.x;
    const int m0 = blockIdx.y * 64, n0 = blockIdx.x * 64;
    const int lr = tid >> 2;
    const int lk = (tid & 3) * 4;
    const int tm = (tid >> 4) * 4;
    const int tn = (tid & 15) * 4;

    float acc[4][4];
    #pragma unroll
    for (int i = 0; i < 4; ++i)
        #pragma unroll
        for (int j = 0; j < 4; ++j) acc[i][j] = 0.f;

    for (int kc = 0; kc < D; kc += 16) {
        const uint2 ua = *(const uint2*)(encB + (size_t)(m0 + lr) * D + kc + lk);
        float a0, a1, a2, a3;
        bf2x(ua.x, a0, a1); bf2x(ua.y, a2, a3);
        const float4 b4 = *(const float4*)(mW + (size_t)(n0 + lr) * D + kc + lk);
        As[(lk + 0) * 64 + lr] = a0; As[(lk + 1) * 64 + lr] = a1;
        As[(lk + 2) * 64 + lr] = a2; As[(lk + 3) * 64 + lr] = a3;
        Bs[(lk + 0) * 64 + lr] = b4.x; Bs[(lk + 1) * 64 + lr] = b4.y;
        Bs[(lk + 2) * 64 + lr] = b4.z; Bs[(lk + 3) * 64 + lr] = b4.w;
        __syncthreads();
        #pragma unroll
        for (int k = 0; k < 16; ++k) {
            const float4 av = *(const float4*)(As + k * 64 + tm);
            const float4 bv = *(const float4*)(Bs + k * 64 + tn);
            acc[0][0] = fmaf(av.x, bv.x, acc[0][0]); acc[0][1] = fmaf(av.x, bv.y, acc[0][1]);
            acc[0][2] = fmaf(av.x, bv.z, acc[0][2]); acc[0][3] = fmaf(av.x, bv.w, acc[0][3]);
            acc[1][0] = fmaf(av.y, bv.x, acc[1][0]); acc[1][1] = fmaf(av.y, bv.y, acc[1][1]);
            acc[1][2] = fmaf(av.y, bv.z, acc[1][2]); acc[1][3] = fmaf(av.y, bv.w, acc[1][3]);
            acc[2][0] = fmaf(av.z, bv.x, acc[2][0]); acc[2][1] = fmaf(av.z, bv.y, acc[2][1]);
            acc[2][2] = fmaf(av.z, bv.z, acc[2][2]); acc[2][3] = fmaf(av.z, bv.w, acc[2][3]);
            acc[3][0] = fmaf(av.w, bv.x, acc[3][0]); acc[3][1] = fmaf(av.w, bv.y, acc[3][1]);
            acc[3][2] = fmaf(av.w, bv.z, acc[3][2]); acc[3][3] = fmaf(av.w, bv.w, acc[3][3]);
        }
        __syncthreads();
    }
    const float bb0 = mb[n0 + tn + 0], bb1 = mb[n0 + tn + 1];
    const float bb2 = mb[n0 + tn + 2], bb3 = mb[n0 + tn + 3];
    #pragma unroll
    for (int i = 0; i < 4; ++i) {
        __hip_bfloat16* row = memB + (size_t)(m0 + tm + i) * D + n0 + tn;
        row[0] = __float2bfloat16(acc[i][0] + bb0);
        row[1] = __float2bfloat16(acc[i][1] + bb1);
        row[2] = __float2bfloat16(acc[i][2] + bb2);
        row[3] = __float2bfloat16(acc[i][3] + bb3);
    }
}

// ---------------- decoder phase: q (blocks 0..191) ----------------
__device__ __forceinline__ void dec_q(
    const float* __restrict__ qW, const float* __restrict__ qb,
    const float* __restrict__ hrd, float* __restrict__ qT, float* __restrict__ lds_h)
{
    const int tid = threadIdx.x;
    const int b   = tid & 63;
    const int jw  = __builtin_amdgcn_readfirstlane((int)(blockIdx.x * 4 + (tid >> 6)));
    const float* w = qW + (size_t)jw * D;
    float acc = 0.f;
    for (int kc = 0; kc < D; kc += 64) {
        const float4* gh = (const float4*)(hrd + kc * 64);
        float4* lh = (float4*)lds_h;
        #pragma unroll
        for (int it = 0; it < 4; ++it) lh[tid + 256 * it] = gh[tid + 256 * it];
        __syncthreads();
        #pragma unroll
        for (int kk = 0; kk < 64; kk += 4) {
            const float4 w4 = *(const float4*)(w + kc + kk);
            acc = fmaf(w4.x, lds_h[(kk + 0) * 64 + b], acc);
            acc = fmaf(w4.y, lds_h[(kk + 1) * 64 + b], acc);
            acc = fmaf(w4.z, lds_h[(kk + 2) * 64 + b], acc);
            acc = fmaf(w4.w, lds_h[(kk + 3) * 64 + b], acc);
        }
        __syncthreads();
    }
    stG(qT + (size_t)b * D + jw, acc + qb[jw]);   // write-through; attn reads coherently
}

// ---------------- decoder phase: tanh-attention, 4 ctx partials (all 256 blocks) ----------------
__device__ __forceinline__ void dec_attn(
    const float* __restrict__ qT, const __hip_bfloat16* __restrict__ memB,
    const __hip_bfloat16* __restrict__ encB, const float* __restrict__ pW,
    const float* __restrict__ pb, float* __restrict__ ctxP, float* __restrict__ seP,
    float* __restrict__ sm)
{
    const int tid = threadIdx.x;
    const int b  = blockIdx.x & 63;
    const int ch = blockIdx.x >> 6;
    float* s_q  = sm;
    float* s_pw = sm + 768;
    float* s_cx = sm + 1536;
    float* s_se = sm + 2304;
    for (int i = tid; i < 768; i += 256) {
        s_q[i]  = ldGf(qT + (size_t)b * D + i);   // coherent read (qT reused every t)
        s_pw[i] = pW[i];
        s_cx[i] = 0.f;
    }
    if (tid == 0) s_se[0] = 0.f;
    __syncthreads();
    const int lane = tid & 63;
    const int wv   = tid >> 6;
    float cacc[12];
    #pragma unroll
    for (int i = 0; i < 12; ++i) cacc[i] = 0.f;
    float seacc = 0.f;
    const float pbv = pb[0];
    const int s0 = ch * 75;
    for (int s = s0 + wv; s < s0 + 75; s += 4) {
        const __hip_bfloat16* mrow = memB + ((size_t)b * SEQ + s) * D;
        const __hip_bfloat16* erow = encB + ((size_t)b * SEQ + s) * D;
        float lp = 0.f;
        #pragma unroll
        for (int g = 0; g < 3; ++g) {
            const int d0 = g * 256 + lane * 4;
            const uint2 mu = *(const uint2*)(mrow + d0);
            float m0, m1, m2, m3;
            bf2x(mu.x, m0, m1); bf2x(mu.y, m2, m3);
            const float4 qv = *(const float4*)(s_q + d0);
            const float4 pv = *(const float4*)(s_pw + d0);
            lp = fmaf(pv.x, tanhfast(m0 + qv.x), lp);
            lp = fmaf(pv.y, tanhfast(m1 + qv.y), lp);
            lp = fmaf(pv.z, tanhfast(m2 + qv.z), lp);
            lp = fmaf(pv.w, tanhfast(m3 + qv.w), lp);
        }
        #pragma unroll
        for (int o = 32; o > 0; o >>= 1) lp += __shfl_xor(lp, o, 64);
        const float e = __expf(lp + pbv);
        seacc += e;
        #pragma unroll
        for (int g = 0; g < 3; ++g) {
            const int d0 = g * 256 + lane * 4;
            const uint2 eu = *(const uint2*)(erow + d0);
            float e0, e1, e2, e3;
            bf2x(eu.x, e0, e1); bf2x(eu.y, e2, e3);
            cacc[g * 4 + 0] = fmaf(e, e0, cacc[g * 4 + 0]);
            cacc[g * 4 + 1] = fmaf(e, e1, cacc[g * 4 + 1]);
            cacc[g * 4 + 2] = fmaf(e, e2, cacc[g * 4 + 2]);
            cacc[g * 4 + 3] = fmaf(e, e3, cacc[g * 4 + 3]);
        }
    }
    #pragma unroll
    for (int g = 0; g < 3; ++g) {
        const int d0 = g * 256 + lane * 4;
        atomicAdd(&s_cx[d0 + 0], cacc[g * 4 + 0]);
        atomicAdd(&s_cx[d0 + 1], cacc[g * 4 + 1]);
        atomicAdd(&s_cx[d0 + 2], cacc[g * 4 + 2]);
        atomicAdd(&s_cx[d0 + 3], cacc[g * 4 + 3]);
    }
    if (lane == 0) atomicAdd(&s_se[0], seacc);
    __syncthreads();
    for (int i = tid; i < 768; i += 256)
        stG(ctxP + ((size_t)ch * 768 + i) * 64 + b, s_cx[i]);   // write-through partials
    if (tid == 0) stG(seP + ch * 64 + b, s_se[0]);
}

// ---------------- decoder phase: combine 4 partials -> unique-per-t buffers (blocks 0..63) ----------------
__device__ __forceinline__ void dec_combine(
    const float* __restrict__ ctxP, const float* __restrict__ seP,
    float* __restrict__ ctxCt, float* __restrict__ seCt)
{
    const int b = blockIdx.x;           // < 64
    const int tid = threadIdx.x;
    for (int i = tid; i < 768; i += 256) {
        float s = ldGf(ctxP + (size_t)i * 64 + b)
                + ldGf(ctxP + (size_t)(768 + i) * 64 + b)
                + ldGf(ctxP + (size_t)(1536 + i) * 64 + b)
                + ldGf(ctxP + (size_t)(2304 + i) * 64 + b);
        stG(ctxCt + (size_t)i * 64 + b, s);     // fresh lines: cell reads cached
    }
    if (tid == 0) {
        float s = ldGf(seP + b) + ldGf(seP + 64 + b) + ldGf(seP + 128 + b) + ldGf(seP + 192 + b);
        stG(seCt + b, s);
    }
}

// ---------------- decoder phase: GRU cell + pred (blocks 0..191) ----------------
__device__ __forceinline__ void dec_cell(
    const float* __restrict__ Wc, const float* __restrict__ W0,
    const float* __restrict__ dWhh, const float* __restrict__ dbih,
    const float* __restrict__ dbhh, const float* __restrict__ tW,
    const float* __restrict__ ctxCt, const float* __restrict__ seCt,
    const float* __restrict__ lastT, float* __restrict__ lastN,
    const float* __restrict__ hrd, float* __restrict__ hwr,
    float* __restrict__ out, int t,
    float* __restrict__ lds_h, float* __restrict__ lds_c)
{
    const int tid = threadIdx.x;
    const int b   = tid & 63;
    const int jw  = __builtin_amdgcn_readfirstlane((int)(blockIdx.x * 4 + (tid >> 6)));
    const float* whr = dWhh + (size_t)jw * D;
    const float* whz = dWhh + (size_t)(768 + jw) * D;
    const float* whn = dWhh + (size_t)(1536 + jw) * D;
    const float* wcr = Wc + (size_t)jw * D;
    const float* wcz = Wc + (size_t)(768 + jw) * D;
    const float* wcn = Wc + (size_t)(1536 + jw) * D;
    float cir = 0.f, ciz = 0.f, cin_ = 0.f, ahr = 0.f, ahz = 0.f, ahn = 0.f;
    for (int kc = 0; kc < D; kc += 64) {
        const float4* gh = (const float4*)(hrd + kc * 64);
        const float4* g0 = (const float4*)(ctxCt + (size_t)kc * 64);
        float4* lh = (float4*)lds_h;
        float4* lc = (float4*)lds_c;
        #pragma unroll
        for (int it = 0; it < 4; ++it) {
            lh[tid + 256 * it] = gh[tid + 256 * it];
            lc[tid + 256 * it] = g0[tid + 256 * it];
        }
        __syncthreads();
        #pragma unroll
        for (int kk = 0; kk < 64; kk += 4) {
            const float4 v0 = *(const float4*)(wcr + kc + kk);
            const float4 v1 = *(const float4*)(wcz + kc + kk);
            const float4 v2 = *(const float4*)(wcn + kc + kk);
            const float4 v3 = *(const float4*)(whr + kc + kk);
            const float4 v4 = *(const float4*)(whz + kc + kk);
            const float4 v5 = *(const float4*)(whn + kc + kk);
            const float c0 = lds_c[(kk + 0) * 64 + b];
            const float c1 = lds_c[(kk + 1) * 64 + b];
            const float c2 = lds_c[(kk + 2) * 64 + b];
            const float c3 = lds_c[(kk + 3) * 64 + b];
            const float h0 = lds_h[(kk + 0) * 64 + b];
            const float h1 = lds_h[(kk + 1) * 64 + b];
            const float h2 = lds_h[(kk + 2) * 64 + b];
            const float h3 = lds_h[(kk + 3) * 64 + b];
            DOT4(cir, v0, c0, c1, c2, c3);
            DOT4(ciz, v1, c0, c1, c2, c3);
            DOT4(cin_, v2, c0, c1, c2, c3);
            DOT4(ahr, v3, h0, h1, h2, h3);
            DOT4(ahz, v4, h0, h1, h2, h3);
            DOT4(ahn, v5, h0, h1, h2, h3);
        }
        __syncthreads();
    }
    const float se = seCt[b];
    const float inv = 1.f / se;
    const float lst = lastT[b];
    const float gir = cir * inv + W0[jw] * lst + dbih[jw];
    const float giz = ciz * inv + W0[768 + jw] * lst + dbih[768 + jw];
    const float gin = cin_ * inv + W0[1536 + jw] * lst + dbih[1536 + jw];
    const float r = sigf(gir + ahr + dbhh[jw]);
    const float z = sigf(giz + ahz + dbhh[768 + jw]);
    const float n = tanhfast(gin + r * (ahn + dbhh[1536 + jw]));
    const float ho = hrd[jw * 64 + b];
    const float hn = (1.f - z) * n + z * ho;
    stG(hwr + jw * 64 + b, hn);

    __syncthreads();
    lds_h[(tid >> 6) * 64 + b] = tW[jw] * hn;
    __syncthreads();
    if (tid < 64) {
        const float p = lds_h[tid] + lds_h[64 + tid] + lds_h[128 + tid] + lds_h[192 + tid];
        atomicAdd(&out[(size_t)tid * TDEC + t], p);
        atomicAdd(&lastN[tid], p);
    }
}

// ---------------- kDecPersist: whole decoder in ONE launch ----------------
__global__ __launch_bounds__(256) void kDecPersist(
    const float* __restrict__ Wc, const float* __restrict__ W0,
    const float* __restrict__ dWhh, const float* __restrict__ dbih,
    const float* __restrict__ dbhh, const float* __restrict__ tW,
    const float* __restrict__ qW, const float* __restrict__ qb,
    const __hip_bfloat16* __restrict__ memB, const __hip_bfloat16* __restrict__ encB,
    const float* __restrict__ pW, const float* __restrict__ pb,
    float* __restrict__ ctxP, float* __restrict__ seP,
    float* __restrict__ ctxC, float* __restrict__ seC, float* __restrict__ lastP,
    float* __restrict__ hDs, float* __restrict__ qT, float* __restrict__ out, u32* bar)
{
    __shared__ float smem[8192];
    u32 bars = 0;
    for (int t = 0; t < TDEC; ++t) {
        const float* hr = hDs + (size_t)t * NH;
        float*       hw = hDs + (size_t)(t + 1) * NH;
        if (blockIdx.x < 192) dec_q(qW, qb, hr, qT, smem);
        gridbar(bar, ++bars);
        dec_attn(qT, memB, encB, pW, pb, ctxP, seP, smem);
        gridbar(bar, ++bars);
        if (blockIdx.x < 64) dec_combine(ctxP, seP, ctxC + (size_t)t * NH, seC + (size_t)t * 64);
        gridbar(bar, ++bars);
        if (blockIdx.x < 192) dec_cell(Wc, W0, dWhh, dbih, dbhh, tW,
                                       ctxC + (size_t)t * NH, seC + (size_t)t * 64,
                                       lastP + t * 64, lastP + (t + 1) * 64,
                                       hr, hw, out, t, smem, smem + 4096);
        gridbar(bar, ++bars);
    }
}

// ---------------- launch ----------------
extern "C" void kernel_launch(void* const* d_in, const int* in_sizes, int n_in,
                              void* d_out, int out_size, void* d_ws, size_t ws_size,
                              hipStream_t stream) {
    const float* x    = (const float*)d_in[0];
    const float* eWih = (const float*)d_in[1];
    const float* eWhh = (const float*)d_in[2];
    const float* ebih = (const float*)d_in[3];
    const float* ebhh = (const float*)d_in[4];
    const float* dWih = (const float*)d_in[5];
    const float* dWhh = (const float*)d_in[6];
    const float* dbih = (const float*)d_in[7];
    const float* dbhh = (const float*)d_in[8];
    const float* qW   = (const float*)d_in[9];
    const float* qb   = (const float*)d_in[10];
    const float* mW   = (const float*)d_in[11];
    const float* mb   = (const float*)d_in[12];
    const float* pW   = (const float*)d_in[13];
    const float* pb   = (const float*)d_in[14];
    const float* tW   = (const float*)d_in[15];
    const float* tb   = (const float*)d_in[16];
    float* out = (float*)d_out;

    char* w = (char*)d_ws;
    auto alloc = [&](size_t bytes) -> char* {
        char* p = w; w += (bytes + 255) & ~(size_t)255; return p;
    };
    // total ~173 MB
    float* Wc    = (float*)alloc((size_t)G3 * D * 4);
    float* W0    = (float*)alloc((size_t)G3 * 4);
    __hip_bfloat16* encB = (__hip_bfloat16*)alloc((size_t)BS * SEQ * D * 2);
    __hip_bfloat16* memB = (__hip_bfloat16*)alloc((size_t)BS * SEQ * D * 2);
    __hip_bfloat16* giB  = (__hip_bfloat16*)alloc((size_t)TCH * G3 * 64 * 2);
    float* hSeq  = (float*)alloc((size_t)(SEQ + 1) * NH * 4);    // unique h per enc step
    float* hDs   = (float*)alloc((size_t)(TDEC + 1) * NH * 4);   // unique h per dec step
    float* qT    = (float*)alloc((size_t)BS * D * 4);
    float* ctxP  = (float*)alloc((size_t)4 * D * 64 * 4);        // partial ring (IF-only)
    float* seP   = (float*)alloc(4 * 64 * 4);                    // partial ring (IF-only)
    float* ctxC  = (float*)alloc((size_t)TDEC * NH * 4);         // combined ctx, unique per t
    float* seC   = (float*)alloc((size_t)TDEC * 64 * 4);         // combined se, unique per t
    float* lastP = (float*)alloc((TDEC + 1) * 64 * 4);
    u32*   barW  = (u32*)alloc(2 * BARWORDS * 4);                // [0]=enc, [1]=dec

    kPrep<<<512, 256, 0, stream>>>(dWih, tb, Wc, W0, hSeq, hDs, lastP, out, barW);
    kEncPersist<<<NBLK, 256, 0, stream>>>(x, eWih, eWhh, ebih, ebhh, giB, hSeq, encB, barW);
    kGemmMem<<<dim3(12, 300), 256, 0, stream>>>(encB, mW, mb, memB);
    kDecPersist<<<NBLK, 256, 0, stream>>>(Wc, W0, dWhh, dbih, dbhh, tW, qW, qb,
                                          memB, encB, pW, pb, ctxP, seP, ctxC, seC, lastP,
                                          hDs, qT, out, barW + BARWORDS);
}